// Round 13
// baseline (182.132 us; speedup 1.0000x reference)
//
#include <hip/hip_runtime.h>

// Problem constants: N=2048, L=4096, M=512, P=512
#define NN 2048
#define LL 4096
#define MM 512
#define PP 512

#define NBLOCKS 256
#define NTHREADS 1024
#define WPB 16                 // waves per block
#define SWEEPS 13              // tanh-Jacobi sweeps after eps0 = tanh(a/Lam)
#define RICH 10                // Richardson iterations for E x = b

typedef unsigned short ushort_t;
typedef unsigned int   uint_t;
typedef unsigned long long ull_t;

__device__ __forceinline__ float wave_reduce_sum(float v) {
#pragma unroll
    for (int off = 32; off > 0; off >>= 1) v += __shfl_xor(v, off, 64);
    return v;
}

__device__ __forceinline__ ushort_t f2bf(float f) {  // RNE float->bf16
    uint_t x = __float_as_uint(f);
    uint_t r = ((x >> 16) & 1u) + 0x7fffu;
    return (ushort_t)((x + r) >> 16);
}
__device__ __forceinline__ uint_t pack2(float lo, float hi) {
    return (uint_t)f2bf(lo) | ((uint_t)f2bf(hi) << 16);
}
__device__ __forceinline__ float bflo(uint_t w) { return __uint_as_float(w << 16); }
__device__ __forceinline__ float bfhi(uint_t w) { return __uint_as_float(w & 0xffff0000u); }
__device__ __forceinline__ int swz(int j) { return j ^ ((j >> 3) & 7); }

__device__ __forceinline__ uint4 cvt8(float4 f0, float4 f1) {
    uint4 o;
    o.x = pack2(f0.x, f0.y); o.y = pack2(f0.z, f0.w);
    o.z = pack2(f1.x, f1.y); o.w = pack2(f1.z, f1.w);
    return o;
}
__device__ __forceinline__ float dot8(uint4 w, float4 e0, float4 e1, float acc) {
    acc = fmaf(bflo(w.x), e0.x, acc); acc = fmaf(bfhi(w.x), e0.y, acc);
    acc = fmaf(bflo(w.y), e0.z, acc); acc = fmaf(bfhi(w.y), e0.w, acc);
    acc = fmaf(bflo(w.z), e1.x, acc); acc = fmaf(bfhi(w.z), e1.y, acc);
    acc = fmaf(bflo(w.w), e1.z, acc); acc = fmaf(bfhi(w.w), e1.w, acc);
    return acc;
}

// Tagged 8-byte publish: {float value (lo), int tag (hi)} in ONE relaxed
// agent-scope atomic — value and tag move atomically. Proven cross-XCD
// coherent (rounds 7/8/11).
__device__ __forceinline__ void tstore(float2* p, float v, int tag) {
    ull_t pk = (ull_t)__float_as_uint(v) | ((ull_t)(uint_t)tag << 32);
    __hip_atomic_store((ull_t*)p, pk, __ATOMIC_RELAXED, __HIP_MEMORY_SCOPE_AGENT);
}

// Stage a tagged vector (NENT entries) into LDS (values only, swizzled).
// Each thread polls its K = NENT/NTHREADS interleaved entries until all
// carry tag >= want. Determinism: a producer publishes tag s+1 only after
// fully consuming tag s, so entries can't be overwritten while awaited.
template<int NENT>
__device__ __forceinline__ void stage_vec(const float2* buf, int want,
                                          float* ev, int tid) {
    constexpr int K = NENT / NTHREADS;
    const ull_t* p = reinterpret_cast<const ull_t*>(buf);
    ull_t u[K];
    for (;;) {
        int tmin = 0x7fffffff;
#pragma unroll
        for (int k = 0; k < K; ++k) {
            u[k] = __hip_atomic_load(p + tid + k * NTHREADS, __ATOMIC_RELAXED,
                                     __HIP_MEMORY_SCOPE_AGENT);
            tmin = min(tmin, (int)(u[k] >> 32));
        }
        if (tmin >= want) break;
        __builtin_amdgcn_s_sleep(1);
    }
#pragma unroll
    for (int k = 0; k < K; ++k) {
        int e = tid + k * NTHREADS;                 // entry index
        ev[(swz(e >> 2) << 2) | (e & 3)] = __uint_as_float((uint_t)u[k]);
    }
}

struct KArgs {
    const float *x, *u, *C1, *D11, *D12, *Lam, *F, *B1, *B2, *E, *C2, *D21, *D22;
    const float *bv, *bx, *bu;
    const int* t;
    float* yout; float* xout;
    float2 *epsA, *epsB, *bT, *xaT, *xbT;   // tagged vectors
};

// Clears all tagged buffers (14336 x 8B) every call — graph-replay safe.
__global__ __launch_bounds__(512) void clear_tags(ull_t* p) {
    p[blockIdx.x * 512 + threadIdx.x] = 0ull;
}

__device__ __forceinline__ float dot_f32(const float* __restrict__ Mrow,
                                         const float* __restrict__ v,
                                         int n, int lane) {
    const float4* Mr = reinterpret_cast<const float4*>(Mrow);
    const float4* V  = reinterpret_cast<const float4*>(v);
    float acc = 0.f;
    int nv = n >> 2;
    for (int c = lane; c < nv; c += 64) {
        float4 m = Mr[c], vv = V[c];
        acc = fmaf(m.x, vv.x, acc); acc = fmaf(m.y, vv.y, acc);
        acc = fmaf(m.z, vv.z, acc); acc = fmaf(m.w, vv.w, acc);
    }
    return acc;
}

// dot of fp32 global row against LDS-staged swizzled vector (nf4 float4)
__device__ __forceinline__ float dot_lds_f32(const float* __restrict__ Mrow,
                                             const float4* evec, int nf4, int lane) {
    const float4* Mr = reinterpret_cast<const float4*>(Mrow);
    float acc = 0.f;
    for (int c = lane; c < nf4; c += 64) {
        float4 m = Mr[c];
        float4 e = evec[swz(c)];
        acc = fmaf(m.x, e.x, acc); acc = fmaf(m.y, e.y, acc);
        acc = fmaf(m.z, e.z, acc); acc = fmaf(m.w, e.w, acc);
    }
    return acc;
}

__global__ __launch_bounds__(NTHREADS, 4) void fused_kernel(KArgs A) {
    const int tid  = threadIdx.x;
    const int lane = tid & 63;
    const int warp = tid >> 6;
    const int W    = blockIdx.x * WPB + warp;       // 0..4095: one D11 row/wave

    __shared__ float4 evec[1024];                   // 16 KB value staging
    float* ev = reinterpret_cast<float*>(evec);

    const float decay = __powf(0.95f, (float)(*A.t));

    // ---- Phase A1: a-row (critical path — publish eps0 ASAP) --------------
    float a_r, lam_r;
    {
        float acc = dot_f32(A.C1 + (size_t)W * NN, A.x, NN, lane)
                  + dot_f32(A.D12 + (size_t)W * MM, A.u, MM, lane);
        acc = wave_reduce_sum(acc);
        lam_r = A.Lam[W];
        a_r = fmaf(decay, A.bv[W], acc);
        if (lane == 0) tstore(&A.epsA[W], tanhf(a_r / lam_r), 1);
    }

    // ---- Phase A2: q (W<NN), y0 (W<PP) — stay in registers -----------------
    float q_r = 0.f, y0_r = 0.f;
    if (W < NN) {
        float acc = dot_f32(A.F + (size_t)W * NN, A.x, NN, lane)
                  + dot_f32(A.B2 + (size_t)W * MM, A.u, MM, lane);
        acc = wave_reduce_sum(acc);
        q_r = fmaf(decay, A.bx[W], acc);
    }
    if (W < PP) {
        float acc = dot_f32(A.C2 + (size_t)W * NN, A.x, NN, lane)
                  + dot_f32(A.D22 + (size_t)W * MM, A.u, MM, lane);
        acc = wave_reduce_sum(acc);
        y0_r = fmaf(decay, A.bu[W], acc);
    }

    // ---- Phase A3: matrix rows -> bf16 registers (guarded, small batches) --
    const int nh8   = (W + 7) >> 3;        // uint4 chunks covering cols [0,W)
    const int kkmax = (nh8 + 63) >> 6;     // wave-uniform chunk bound (<=8)
    uint4 rd[8], gr[4];
    {
        const float4* Dr = reinterpret_cast<const float4*>(A.D11 + (size_t)W * LL);
#pragma unroll
        for (int kk = 0; kk < 8; ++kk) {
            int c = kk * 64 + lane;
            rd[kk] = make_uint4(0u, 0u, 0u, 0u);
            if (c < nh8) rd[kk] = cvt8(Dr[2 * c], Dr[2 * c + 1]);
        }
    }
    if (W < NN) {   // G = I - E, row W, bf16
        const float4* Er = reinterpret_cast<const float4*>(A.E + (size_t)W * NN);
#pragma unroll
        for (int kk = 0; kk < 4; ++kk) {
            int c = kk * 64 + lane;
            float4 f0 = Er[2 * c], f1 = Er[2 * c + 1];
            int g0 = 8 * c;
            float e[8] = {f0.x, f0.y, f0.z, f0.w, f1.x, f1.y, f1.z, f1.w};
            uint_t wd[4];
#pragma unroll
            for (int j2 = 0; j2 < 4; ++j2) {
                float glo = ((g0 + 2 * j2)     == W ? 1.f : 0.f) - e[2 * j2];
                float ghi = ((g0 + 2 * j2 + 1) == W ? 1.f : 0.f) - e[2 * j2 + 1];
                wd[j2] = pack2(glo, ghi);
            }
            gr[kk] = make_uint4(wd[0], wd[1], wd[2], wd[3]);
        }
    } else {
#pragma unroll
        for (int kk = 0; kk < 4; ++kk) gr[kk] = make_uint4(0u, 0u, 0u, 0u);
    }

    // ---- Phase B: tanh-Jacobi sweeps — tagged dataflow, no barriers -------
    // Invariant: sweep s reads tag s from in, writes tag s+1 to out.
    for (int s = 1; s <= SWEEPS; ++s) {
        const float2* in = (s & 1) ? A.epsA : A.epsB;
        float2*      out = (s & 1) ? A.epsB : A.epsA;
        stage_vec<LL>(in, s, ev, tid);
        __syncthreads();
        float sum = 0.f;
#pragma unroll
        for (int kk = 0; kk < 8; ++kk) {         // static reg index (rule #20)
            if (kk < kkmax) {                    // wave-uniform skip
                int c = kk * 64 + lane;
                float4 e0 = evec[swz(2 * c)], e1 = evec[swz(2 * c + 1)];
                sum = dot8(rd[kk], e0, e1, sum);
            }
        }
        sum = wave_reduce_sum(sum);
        if (lane == 0) tstore(&out[W], tanhf((a_r + sum) / lam_r), s + 1);
        __syncthreads();   // all reads of LDS done before next sweep's stage
    }

    // Blocks whose waves are all W>=2048 have no phase C/D work.
    if (blockIdx.x >= NBLOCKS / 2) return;

    // ---- Phase C: y = D21 eps + y0 ; b = B1 eps + q (fp32 global rows) ----
    float b_r;
    {
        const float2* efin = (SWEEPS & 1) ? A.epsB : A.epsA;  // tag SWEEPS+1
        stage_vec<LL>(efin, SWEEPS + 1, ev, tid);
        __syncthreads();
        float acc = dot_lds_f32(A.B1 + (size_t)W * LL, evec, 1024, lane);
        acc = wave_reduce_sum(acc);
        b_r = q_r + acc;
        if (lane == 0) tstore(&A.bT[W], b_r, 1);
        if (W < PP) {
            float ya = dot_lds_f32(A.D21 + (size_t)W * LL, evec, 1024, lane);
            ya = wave_reduce_sum(ya);
            if (lane == 0) A.yout[W] = y0_r + ya;
        }
        __syncthreads();
    }

    // ---- Phase D: Richardson x <- b + G x, dataflow ------------------------
    // Step k reads tag k+1 from (k==0 ? bT : prev buffer), writes tag k+2.
    for (int k = 0; k < RICH; ++k) {
        const float2* xin = (k == 0) ? A.bT : ((k & 1) ? A.xaT : A.xbT);
        float2*       xo  = (k & 1) ? A.xbT : A.xaT;
        stage_vec<NN>(xin, k + 1, ev, tid);
        __syncthreads();
        float acc = 0.f;
#pragma unroll
        for (int kk = 0; kk < 4; ++kk) {
            int c = kk * 64 + lane;
            float4 e0 = evec[swz(2 * c)], e1 = evec[swz(2 * c + 1)];
            acc = dot8(gr[kk], e0, e1, acc);
        }
        acc = wave_reduce_sum(acc);
        float val = b_r + acc;
        if (lane == 0) {
            if (k == RICH - 1) A.xout[W] = val;            // final: plain store
            else               tstore(&xo[W], val, k + 2);
        }
        __syncthreads();
    }
}

extern "C" void kernel_launch(void* const* d_in, const int* in_sizes, int n_in,
                              void* d_out, int out_size, void* d_ws, size_t ws_size,
                              hipStream_t stream) {
    KArgs A;
    A.x   = (const float*)d_in[0];
    A.u   = (const float*)d_in[1];
    A.C1  = (const float*)d_in[2];
    A.D11 = (const float*)d_in[3];
    A.D12 = (const float*)d_in[4];
    A.Lam = (const float*)d_in[5];
    A.F   = (const float*)d_in[6];
    A.B1  = (const float*)d_in[7];
    A.B2  = (const float*)d_in[8];
    A.E   = (const float*)d_in[9];
    A.C2  = (const float*)d_in[10];
    A.D21 = (const float*)d_in[11];
    A.D22 = (const float*)d_in[12];
    A.bv  = (const float*)d_in[13];
    A.bx  = (const float*)d_in[14];
    A.bu  = (const float*)d_in[15];
    A.t   = (const int*)d_in[16];
    A.yout = (float*)d_out;
    A.xout = (float*)d_out + PP;

    // Tagged buffers, contiguous from ws start: 14336 x 8B = 114,688 bytes
    float2* f2 = (float2*)d_ws;
    A.epsA = f2;            // 4096
    A.epsB = f2 + 4096;     // 4096
    A.bT   = f2 + 8192;     // 2048
    A.xaT  = f2 + 10240;    // 2048
    A.xbT  = f2 + 12288;    // 2048  (total 14336)

    clear_tags<<<28, 512, 0, stream>>>((ull_t*)d_ws);   // 28*512 = 14336

    void* params[] = { &A };
    hipLaunchCooperativeKernel((const void*)fused_kernel, dim3(NBLOCKS),
                               dim3(NTHREADS), params, 0, stream);
}